// Round 15
// baseline (210.492 us; speedup 1.0000x reference)
//
#include <hip/hip_runtime.h>
#include <hip/hip_bf16.h>

typedef short bf16x8 __attribute__((ext_vector_type(8)));
typedef float f32x4 __attribute__((ext_vector_type(4)));
typedef int   i32x4 __attribute__((ext_vector_type(4)));
typedef unsigned u32x2 __attribute__((ext_vector_type(2)));
typedef unsigned short u16;

constexpr int TOKS = 2048;
constexpr int EMB  = 2048;
constexpr int NH   = 16;
constexpr int HS   = 128;
constexpr float RSQ = 0.08838834764831845f; // 1/sqrt(128)

// workspace layout (bytes)
constexpr size_t OFF_SCAL = 0;                       // 4 floats (absmax)
constexpr size_t OFF_QX   = 1024;                    // int8 x [T,EMB] (4MB used)
constexpr size_t SZ_MAT   = (size_t)TOKS * EMB * 2;  // 8MB bf16
constexpr size_t OFF_QW   = OFF_QX + SZ_MAT;         // int8 x 3 mats (12MB used)
constexpr size_t OFF_Q    = OFF_QW + 3 * SZ_MAT;
constexpr size_t OFF_K    = OFF_Q + SZ_MAT;
constexpr size_t OFF_V    = OFF_K + SZ_MAT;
constexpr size_t OFF_VT   = OFF_V + SZ_MAT;
constexpr size_t OFF_DEN  = OFF_VT + SZ_MAT;         // invden, 8MB bf16
// partial attn outputs overlay qx8/qw8 (dead after k_gemm): 2 x 16MB f32
constexpr size_t OFF_P0   = OFF_QX;
constexpr size_t OFF_P1   = OFF_QX + (size_t)NH * TOKS * HS * 4;

#define VMCNT(n) asm volatile("s_waitcnt vmcnt(" #n ")" ::: "memory")
#define LGKM0()  asm volatile("s_waitcnt lgkmcnt(0)" ::: "memory")
#define BAR()    do { asm volatile("" ::: "memory"); __builtin_amdgcn_s_barrier(); asm volatile("" ::: "memory"); } while (0)

__device__ __forceinline__ u16 f2b(float f) {
  unsigned u = __float_as_uint(f);
  unsigned r = (u + 0x7fffu + ((u >> 16) & 1u)) >> 16;
  return (u16)r;
}

__device__ __forceinline__ unsigned cvtpk(float a, float b) {
  unsigned r;
  asm("v_cvt_pk_bf16_f32 %0, %1, %2" : "=v"(r) : "v"(a), "v"(b));
  return r;
}

__device__ __forceinline__ void gload16(const void* g, void* l) {
  __builtin_amdgcn_global_load_lds(
      (const __attribute__((address_space(1))) unsigned int*)g,
      (__attribute__((address_space(3))) unsigned int*)l, 16, 0, 0);
}

// untracked register loads (counted only by our manual VMCNT)
__device__ __forceinline__ bf16x8 gload_dx4(const void* p) {
  bf16x8 r;
  asm volatile("global_load_dwordx4 %0, %1, off" : "=v"(r) : "v"(p));
  return r;
}
__device__ __forceinline__ u32x2 gload_dx2(const void* p) {
  u32x2 r;
  asm volatile("global_load_dwordx2 %0, %1, off" : "=v"(r) : "v"(p));
  return r;
}

__global__ void k_init(int* scal) {
  if (threadIdx.x < 4) scal[threadIdx.x] = 0;
}

__global__ void k_absmax(const float* __restrict__ x, const float* __restrict__ w1,
                         const float* __restrict__ w2, const float* __restrict__ w3,
                         int* scal) {
  const float* src = (blockIdx.y == 0) ? x : (blockIdx.y == 1) ? w1 : (blockIdx.y == 2) ? w2 : w3;
  const float4* s4 = (const float4*)src;
  int idx = blockIdx.x * 256 + threadIdx.x;
  float m = 0.f;
  for (int i = 0; i < 16; ++i) {
    float4 v = s4[idx + i * 65536];
    m = fmaxf(m, fmaxf(fmaxf(fabsf(v.x), fabsf(v.y)), fmaxf(fabsf(v.z), fabsf(v.w))));
  }
  for (int o = 32; o; o >>= 1) m = fmaxf(m, __shfl_down(m, o));
  __shared__ float red[4];
  if ((threadIdx.x & 63) == 0) red[threadIdx.x >> 6] = m;
  __syncthreads();
  if (threadIdx.x == 0) {
    m = fmaxf(fmaxf(red[0], red[1]), fmaxf(red[2], red[3]));
    atomicMax(&scal[blockIdx.y], __float_as_int(m));
  }
}

// quantize to int8 codes (exact)
__global__ void k_quant(const float* __restrict__ x, const float* __restrict__ w1,
                        const float* __restrict__ w2, const float* __restrict__ w3,
                        char* qx, char* qw, const int* scal) {
  int a = blockIdx.y;
  const float* src = (a == 0) ? x : (a == 1) ? w1 : (a == 2) ? w2 : w3;
  char* dst = (a == 0) ? qx : qw + (size_t)(a - 1) * TOKS * EMB;
  float mx = __int_as_float(scal[a]);
  float s = (a == 0) ? mx * 0.25f : mx / 3.0f;
  float lo = (a == 0) ? -4.f : -3.f;
  const float hi = 3.f;
  int idx = blockIdx.x * 256 + threadIdx.x;
  for (int i = 0; i < 16; ++i) {
    int j = idx + i * 65536;
    float4 v = ((const float4*)src)[j];
    int i0 = (int)fminf(fmaxf(rintf(v.x / s), lo), hi);
    int i1 = (int)fminf(fmaxf(rintf(v.y / s), lo), hi);
    int i2 = (int)fminf(fmaxf(rintf(v.z / s), lo), hi);
    int i3 = (int)fminf(fmaxf(rintf(v.w / s), lo), hi);
    unsigned o = (unsigned)(unsigned char)i0 | ((unsigned)(unsigned char)i1 << 8) |
                 ((unsigned)(unsigned char)i2 << 16) | ((unsigned)(unsigned char)i3 << 24);
    ((unsigned*)dst)[j] = o;
  }
}

// Fused QKV GEMM in int8: BM=BN=128, BK=128 i8, 16 K-steps, i32 accum (exact).
__global__ __launch_bounds__(256, 3) void k_gemm(const char* __restrict__ qx, const char* __restrict__ qw,
    const float* __restrict__ b1, const float* __restrict__ b2, const float* __restrict__ b3,
    const int* __restrict__ scal, u16* qo, u16* ko, u16* vo) {
  int z = blockIdx.z;
  const char* W = qw + (size_t)z * TOKS * EMB;
  const float* bias = (z == 0) ? b1 : (z == 1) ? b2 : b3;
  u16* out = (z == 0) ? qo : (z == 1) ? ko : vo;
  float sx = __int_as_float(scal[0]) * 0.25f;
  float sw = __int_as_float(scal[1 + z]) / 3.0f;
  float alpha = sx * sw;
  float extra = (z == 0) ? RSQ : 1.0f;
  int t0 = blockIdx.y * 128, o0 = blockIdx.x * 128;
  __shared__ __align__(16) char As[128 * 128];  // 16KB, rows of 128B (128 i8)
  __shared__ __align__(16) char Bs[128 * 128];
  int tid = threadIdx.x, lane = tid & 63, wid = tid >> 6;
  int mh = (wid >> 1) * 64, nh = (wid & 1) * 64;
  i32x4 acc[4][4] = {};
  for (int kk = 0; kk < 16; ++kk) {
#pragma unroll
    for (int p = 0; p < 4; ++p) {
      int L = p * 4096 + tid * 16;
      int r = L >> 7;
      int s = ((L >> 4) & 7) ^ (r & 7);
      gload16(qx + (size_t)(t0 + r) * 2048 + kk * 128 + s * 16,
              As + p * 4096 + wid * 1024);
      gload16(W + (size_t)(o0 + r) * 2048 + kk * 128 + s * 16,
              Bs + p * 4096 + wid * 1024);
    }
    __syncthreads();
#pragma unroll
    for (int ks = 0; ks < 2; ++ks) {
      i32x4 af[4], bfr[4];
#pragma unroll
      for (int m = 0; m < 4; ++m) {
        int row = mh + m * 16 + (lane & 15);
        int sl = (ks * 4 + (lane >> 4)) ^ (row & 7);
        af[m] = *(const i32x4*)(As + row * 128 + sl * 16);
      }
#pragma unroll
      for (int n = 0; n < 4; ++n) {
        int row = nh + n * 16 + (lane & 15);
        int sl = (ks * 4 + (lane >> 4)) ^ (row & 7);
        bfr[n] = *(const i32x4*)(Bs + row * 128 + sl * 16);
      }
#pragma unroll
      for (int m = 0; m < 4; ++m)
#pragma unroll
        for (int n = 0; n < 4; ++n)
          acc[m][n] = __builtin_amdgcn_mfma_i32_16x16x64_i8(af[m], bfr[n], acc[m][n], 0, 0, 0);
    }
    __syncthreads();
  }
#pragma unroll
  for (int m = 0; m < 4; ++m)
#pragma unroll
    for (int n = 0; n < 4; ++n) {
      int ocol = o0 + nh + n * 16 + (lane & 15);
      float bb = bias[ocol];
#pragma unroll
      for (int r = 0; r < 4; ++r) {
        int trow = t0 + mh + m * 16 + (lane >> 4) * 4 + r;
        float v = ((float)acc[m][n][r] * alpha + bb) * extra;
        out[(size_t)trow * EMB + ocol] = f2b(v);
      }
    }
}

__global__ void k_transpose(const u16* __restrict__ v, u16* vt) {
  int h = blockIdx.z, d0 = blockIdx.y * 64, t0 = blockIdx.x * 64;
  __shared__ u16 tile[64][65];
  int tid = threadIdx.x;
  for (int i = 0; i < 16; ++i) {
    int idx = i * 256 + tid, r = idx >> 6, c = idx & 63;
    tile[r][c] = v[(size_t)(t0 + r) * EMB + h * HS + d0 + c];
  }
  __syncthreads();
  for (int i = 0; i < 16; ++i) {
    int idx = i * 256 + tid, r = idx >> 6, c = idx & 63;
    vt[(size_t)(h * HS + d0 + r) * TOKS + t0 + c] = tile[c][r];
  }
}

// denom: invden[q,k] = 1 / sum_h exp(att[h,q,k]), bf16.
// 64q x 64k per block, grid 1024 (4 blocks/CU @ 32KB), 4 waves 2x2, dbuf LDS.
__global__ __launch_bounds__(256, 4) void k_denom(const u16* __restrict__ q, const u16* __restrict__ k,
                                                  u16* __restrict__ invden) {
  int bid = blockIdx.x;
  int kx = bid & 31, qy = bid >> 5;   // same-XCD blocks share a K stripe
  int qt0 = qy * 64, kt0 = kx * 64;
  __shared__ __align__(16) u16 Qs[2][64 * 64];   // 2 x 8KB
  __shared__ __align__(16) u16 Ksm[2][64 * 64];  // 2 x 8KB
  int tid = threadIdx.x, lane = tid & 63, wid = tid >> 6;
  int wq = (wid >> 1) * 32, wk = (wid & 1) * 32;
  f32x4 acc[2][2] = {}, dd[2][2] = {};
  auto stage = [&](int st, int buf) {
#pragma unroll
    for (int p = 0; p < 2; ++p) {
      int L = p * 4096 + tid * 16;
      int r = L >> 7;
      int s = ((L >> 4) & 7) ^ (r & 7);
      gload16((const char*)q + (size_t)(qt0 + r) * 4096 + st * 128 + s * 16,
              (char*)Qs[buf] + p * 4096 + wid * 1024);
      gload16((const char*)k + (size_t)(kt0 + r) * 4096 + st * 128 + s * 16,
              (char*)Ksm[buf] + p * 4096 + wid * 1024);
    }
  };
  stage(0, 0);
  for (int st = 0; st < 32; ++st) {
    int cur = st & 1;
    if (st < 31) { stage(st + 1, cur ^ 1); VMCNT(4); } else { VMCNT(0); }
    BAR();
    __builtin_amdgcn_s_setprio(1);
#pragma unroll
    for (int ks = 0; ks < 2; ++ks) {
      bf16x8 af[2], bfr[2];
#pragma unroll
      for (int m = 0; m < 2; ++m) {
        int row = wq + m * 16 + (lane & 15);
        int sl = (ks * 4 + (lane >> 4)) ^ (row & 7);
        af[m] = *(const bf16x8*)((const char*)Qs[cur] + row * 128 + sl * 16);
      }
#pragma unroll
      for (int n = 0; n < 2; ++n) {
        int row = wk + n * 16 + (lane & 15);
        int sl = (ks * 4 + (lane >> 4)) ^ (row & 7);
        bfr[n] = *(const bf16x8*)((const char*)Ksm[cur] + row * 128 + sl * 16);
      }
#pragma unroll
      for (int m = 0; m < 2; ++m)
#pragma unroll
        for (int n = 0; n < 2; ++n)
          acc[m][n] = __builtin_amdgcn_mfma_f32_16x16x32_bf16(af[m], bfr[n], acc[m][n], 0, 0, 0);
    }
    __builtin_amdgcn_s_setprio(0);
    BAR();
    if (st & 1) {  // head boundary: fold exp(acc) into dd, reset acc
#pragma unroll
      for (int m = 0; m < 2; ++m)
#pragma unroll
        for (int n = 0; n < 2; ++n) {
#pragma unroll
          for (int r = 0; r < 4; ++r) dd[m][n][r] += __expf(acc[m][n][r]);
          acc[m][n] = f32x4{0.f, 0.f, 0.f, 0.f};
        }
    }
  }
#pragma unroll
  for (int m = 0; m < 2; ++m)
#pragma unroll
    for (int n = 0; n < 2; ++n)
#pragma unroll
      for (int r = 0; r < 4; ++r) {
        int qrow = qt0 + wq + m * 16 + (lane >> 4) * 4 + r;
        int kcol = kt0 + wk + n * 16 + (lane & 15);
        invden[(size_t)qrow * TOKS + kcol] = f2b(1.0f / dd[m][n][r]);
      }
}

// attention: 64q x 1 head x HALF the k-range per block, grid 1024.
// K now loaded DIRECTLY global->registers (kA/kB prefetch, untracked asm,
// counted vmcnt) -- no Ks LDS, no DMA. LDS = Ps 8KB only (usable-LDS cap
// kept k_attn at ~2 blocks/CU at 40KB; LDS traffic/iter 72KB -> 40KB).
__global__ __launch_bounds__(256, 2) void k_attn(const u16* __restrict__ q, const u16* __restrict__ k,
                                                 const u16* __restrict__ vt, const u16* __restrict__ invden,
                                                 float* __restrict__ p0, float* __restrict__ p1) {
  int bid = blockIdx.x;
  int h = (bid & 7) * 2 + ((bid >> 3) & 1);  // XCD bid%8 owns a head PAIR -> K/V L2-resident
  int half = (bid >> 4) & 1;
  int qt0 = (bid >> 5) * 64;
  int kb0 = half * 16;
  float* out = half ? p1 : p0;
  __shared__ __align__(16) u16 Ps[64 * 64];  // 8KB single buffer (BAR orders reuse)
  int tid = threadIdx.x, lane = tid & 63, wid = tid >> 6;

  // per-lane bases for register K / V^T / invden loads
  // K[k = kb*64 + wid*16 + (lane&15)][d = c*32 + (lane>>4)*8 .. +8]
  const u16* kbase = k + (size_t)(kb0 * 64 + wid * 16 + (lane & 15)) * EMB
                     + h * HS + (lane >> 4) * 8;
  const u16* vbase = vt + ((size_t)(h * HS + wid * 32 + (lane & 15))) * TOKS
                     + half * 1024 + (lane >> 4) * 8;
  const u16* dvbase = invden + ((size_t)(qt0 + (lane & 15))) * TOKS
                      + half * 1024 + wid * 16 + (lane >> 4) * 4;

  bf16x8 kA[4], kB[4], vA[4], vB[4];
  u32x2 dvA[4], dvB[4];

  // prologue: iter-0 loads (K 4, V 4, dv 2 = 10 in flight)
#pragma unroll
  for (int c = 0; c < 4; ++c)
    kA[c] = gload_dx4(kbase + c * 32);
#pragma unroll
  for (int j = 0; j < 2; ++j)
#pragma unroll
    for (int ks = 0; ks < 2; ++ks)
      vA[j * 2 + ks] = gload_dx4(vbase + (size_t)j * 16 * TOKS + ks * 32);
#pragma unroll
  for (int m = 0; m < 4; ++m)
    dvA[m] = gload_dx2(dvbase + (size_t)m * 16 * TOKS);

  bf16x8 qf[4][4];
#pragma unroll
  for (int m = 0; m < 4; ++m)
#pragma unroll
    for (int c = 0; c < 4; ++c)
      qf[m][c] = *(const bf16x8*)(q + (size_t)(qt0 + m * 16 + (lane & 15)) * EMB
                                  + h * HS + c * 32 + (lane >> 4) * 8);
  f32x4 yacc[4][2] = {};

#define ITER(REL, KU, KP, VU, VP, DVU, DVP, LAST)                               \
  {                                                                             \
    if (!(LAST)) {                                                              \
      _Pragma("unroll")                                                         \
      for (int c = 0; c < 4; ++c)                                               \
        KP[c] = gload_dx4(kbase + (size_t)((REL) + 1) * 64 * EMB + c * 32);     \
      _Pragma("unroll")                                                         \
      for (int j = 0; j < 2; ++j)                                               \
        _Pragma("unroll")                                                       \
        for (int ks = 0; ks < 2; ++ks)                                          \
          VP[j * 2 + ks] = gload_dx4(vbase + (size_t)j * 16 * TOKS +            \
                                     ((REL) + 1) * 64 + ks * 32);               \
      _Pragma("unroll")                                                         \
      for (int m = 0; m < 4; ++m)                                               \
        DVP[m] = gload_dx2(dvbase + (size_t)m * 16 * TOKS + ((REL) + 1) * 64);  \
      VMCNT(10);                                                                \
    } else {                                                                    \
      VMCNT(0);                                                                 \
    }                                                                           \
    __builtin_amdgcn_sched_barrier(0);                                          \
    BAR(); /* prior-iter PV reads of Ps complete before this iter's P-write */  \
    f32x4 pacc[4] = {};                                                         \
    __builtin_amdgcn_s_setprio(1);                                              \
    _Pragma("unroll")                                                           \
    for (int c = 0; c < 4; ++c) {                                               \
      _Pragma("unroll")                                                         \
      for (int m = 0; m < 4; ++m)                                               \
        pacc[m] = __builtin_amdgcn_mfma_f32_16x16x32_bf16(KU[c], qf[m][c], pacc[m], 0, 0, 0); \
    }                                                                           \
    __builtin_amdgcn_s_setprio(0);                                              \
    _Pragma("unroll")                                                           \
    for (int m = 0; m < 4; ++m) {                                               \
      int qr = m * 16 + (lane & 15);                                            \
      float d0 = __uint_as_float(DVU[m][0] << 16);                              \
      float d1 = __uint_as_float(DVU[m][0] & 0xffff0000u);                      \
      float d2 = __uint_as_float(DVU[m][1] << 16);                              \
      float d3 = __uint_as_float(DVU[m][1] & 0xffff0000u);                      \
      float e0 = __expf(pacc[m][0]) * d0;                                       \
      float e1 = __expf(pacc[m][1]) * d1;                                       \
      float e2 = __expf(pacc[m][2]) * d2;                                       \
      float e3 = __expf(pacc[m][3]) * d3;                                       \
      uint2 pk;                                                                 \
      pk.x = cvtpk(e0, e1);                                                     \
      pk.y = cvtpk(e2, e3);                                                     \
      int kby = wid * 32 + (lane >> 4) * 8;                                     \
      *(uint2*)((char*)Ps + qr * 128 + (kby ^ ((qr & 7) << 4))) = pk;           \
    }                                                                           \
    LGKM0();                                                                    \
    BAR();                                                                      \
    __builtin_amdgcn_sched_barrier(0);                                          \
    __builtin_amdgcn_s_setprio(1);                                              \
    _Pragma("unroll")                                                           \
    for (int ks = 0; ks < 2; ++ks) {                                            \
      bf16x8 pa[4];                                                             \
      _Pragma("unroll")                                                         \
      for (int m = 0; m < 4; ++m) {                                             \
        int row = m * 16 + (lane & 15);                                         \
        int off = (ks * 64 + (lane >> 4) * 16) ^ ((row & 7) << 4);              \
        pa[m] = *(const bf16x8*)((const char*)Ps + row * 128 + off);            \
      }                                                                         \
      _Pragma("unroll")                                                         \
      for (int m = 0; m < 4; ++m)                                               \
        _Pragma("unroll")                                                       \
        for (int j = 0; j < 2; ++j)                                             \
          yacc[m][j] = __builtin_amdgcn_mfma_f32_16x16x32_bf16(pa[m], VU[j * 2 + ks], yacc[m][j], 0, 0, 0); \
    }                                                                           \
    __builtin_amdgcn_s_setprio(0);                                              \
  }

  for (int t = 0; t < 7; ++t) {
    ITER(2 * t, kA, kB, vA, vB, dvA, dvB, false);
    ITER(2 * t + 1, kB, kA, vB, vA, dvB, dvA, false);
  }
  ITER(14, kA, kB, vA, vB, dvA, dvB, false);
  ITER(15, kB, kA, vB, vA, dvB, dvA, true);
#undef ITER

#pragma unroll
  for (int m = 0; m < 4; ++m)
#pragma unroll
    for (int j = 0; j < 2; ++j)
#pragma unroll
      for (int r = 0; r < 4; ++r) {
        int trow = qt0 + m * 16 + (lane >> 4) * 4 + r;
        int dcol = wid * 32 + j * 16 + (lane & 15);
        out[(size_t)(h * TOKS + trow) * HS + dcol] = yacc[m][j][r];
      }
}

// y = p0 + p1. out = 4,194,304 floats = 1,048,576 float4s.
// grid 1024 x 256 threads x 4 iters x 1 float4 = exactly 1,048,576.
__global__ void k_merge(const float* __restrict__ p0, const float* __restrict__ p1,
                        float* __restrict__ y) {
  int idx = blockIdx.x * 256 + threadIdx.x;
  const float4* a4 = (const float4*)p0;
  const float4* b4 = (const float4*)p1;
  float4* y4 = (float4*)y;
#pragma unroll
  for (int j = 0; j < 4; ++j) {
    int t = idx + j * 262144;
    float4 a = a4[t], b = b4[t];
    float4 r;
    r.x = a.x + b.x;
    r.y = a.y + b.y;
    r.z = a.z + b.z;
    r.w = a.w + b.w;
    y4[t] = r;
  }
}

extern "C" void kernel_launch(void* const* d_in, const int* in_sizes, int n_in,
                              void* d_out, int out_size, void* d_ws, size_t ws_size,
                              hipStream_t stream) {
  const float* x  = (const float*)d_in[0];
  const float* W1 = (const float*)d_in[1];
  const float* b1 = (const float*)d_in[2];
  const float* W2 = (const float*)d_in[3];
  const float* b2 = (const float*)d_in[4];
  const float* W3 = (const float*)d_in[5];
  const float* b3 = (const float*)d_in[6];
  char* ws = (char*)d_ws;
  int*   scal   = (int*)(ws + OFF_SCAL);
  char*  qx8    = (char*)(ws + OFF_QX);
  char*  qw8    = (char*)(ws + OFF_QW);
  u16*   qo     = (u16*)(ws + OFF_Q);
  u16*   ko     = (u16*)(ws + OFF_K);
  u16*   vo     = (u16*)(ws + OFF_V);
  u16*   vt     = (u16*)(ws + OFF_VT);
  u16*   invden = (u16*)(ws + OFF_DEN);
  float* p0     = (float*)(ws + OFF_P0);
  float* p1     = (float*)(ws + OFF_P1);
  float* y      = (float*)d_out;

  hipLaunchKernelGGL(k_init, dim3(1), dim3(64), 0, stream, scal);
  hipLaunchKernelGGL(k_absmax, dim3(256, 4), dim3(256), 0, stream, x, W1, W2, W3, scal);
  hipLaunchKernelGGL(k_quant, dim3(256, 4), dim3(256), 0, stream, x, W1, W2, W3, qx8, qw8, scal);
  hipLaunchKernelGGL(k_gemm, dim3(16, 16, 3), dim3(256), 0, stream,
                     qx8, qw8, b1, b2, b3, scal, qo, ko, vo);
  hipLaunchKernelGGL(k_transpose, dim3(32, 2, 16), dim3(256), 0, stream, vo, vt);
  hipLaunchKernelGGL(k_denom, dim3(1024), dim3(256), 0, stream, qo, ko, invden);
  hipLaunchKernelGGL(k_attn, dim3(1024), dim3(256), 0, stream, qo, ko, vt, invden, p0, p1);
  hipLaunchKernelGGL(k_merge, dim3(1024), dim3(256), 0, stream, p0, p1, y);
}

// Round 16
// 175.432 us; speedup vs baseline: 1.1999x; 1.1999x over previous
//
#include <hip/hip_runtime.h>
#include <hip/hip_bf16.h>

typedef short bf16x8 __attribute__((ext_vector_type(8)));
typedef float f32x4 __attribute__((ext_vector_type(4)));
typedef int   i32x4 __attribute__((ext_vector_type(4)));
typedef unsigned u32x2 __attribute__((ext_vector_type(2)));
typedef unsigned short u16;

constexpr int TOKS = 2048;
constexpr int EMB  = 2048;
constexpr int NH   = 16;
constexpr int HS   = 128;
constexpr float RSQ = 0.08838834764831845f; // 1/sqrt(128)

// workspace layout (bytes)
constexpr size_t OFF_SCAL = 0;                       // 4 floats (absmax)
constexpr size_t OFF_QX   = 1024;                    // int8 x [T,EMB] (4MB used)
constexpr size_t SZ_MAT   = (size_t)TOKS * EMB * 2;  // 8MB bf16
constexpr size_t OFF_QW   = OFF_QX + SZ_MAT;         // int8 x 3 mats (12MB used)
constexpr size_t OFF_Q    = OFF_QW + 3 * SZ_MAT;
constexpr size_t OFF_K    = OFF_Q + SZ_MAT;
constexpr size_t OFF_V    = OFF_K + SZ_MAT;
constexpr size_t OFF_VT   = OFF_V + SZ_MAT;
constexpr size_t OFF_DEN  = OFF_VT + SZ_MAT;         // invden, 8MB bf16

#define VMCNT(n) asm volatile("s_waitcnt vmcnt(" #n ")" ::: "memory")
#define LGKM0()  asm volatile("s_waitcnt lgkmcnt(0)" ::: "memory")
#define BAR()    do { asm volatile("" ::: "memory"); __builtin_amdgcn_s_barrier(); asm volatile("" ::: "memory"); } while (0)

__device__ __forceinline__ u16 f2b(float f) {
  unsigned u = __float_as_uint(f);
  unsigned r = (u + 0x7fffu + ((u >> 16) & 1u)) >> 16;
  return (u16)r;
}

__device__ __forceinline__ unsigned cvtpk(float a, float b) {
  unsigned r;
  asm("v_cvt_pk_bf16_f32 %0, %1, %2" : "=v"(r) : "v"(a), "v"(b));
  return r;
}

__device__ __forceinline__ void gload16(const void* g, void* l) {
  __builtin_amdgcn_global_load_lds(
      (const __attribute__((address_space(1))) unsigned int*)g,
      (__attribute__((address_space(3))) unsigned int*)l, 16, 0, 0);
}

// untracked register loads (counted only by our manual VMCNT)
__device__ __forceinline__ bf16x8 gload_dx4(const void* p) {
  bf16x8 r;
  asm volatile("global_load_dwordx4 %0, %1, off" : "=v"(r) : "v"(p));
  return r;
}
__device__ __forceinline__ u32x2 gload_dx2(const void* p) {
  u32x2 r;
  asm volatile("global_load_dwordx2 %0, %1, off" : "=v"(r) : "v"(p));
  return r;
}

__global__ void k_init(int* scal) {
  if (threadIdx.x < 4) scal[threadIdx.x] = 0;
}

__global__ void k_absmax(const float* __restrict__ x, const float* __restrict__ w1,
                         const float* __restrict__ w2, const float* __restrict__ w3,
                         int* scal) {
  const float* src = (blockIdx.y == 0) ? x : (blockIdx.y == 1) ? w1 : (blockIdx.y == 2) ? w2 : w3;
  const float4* s4 = (const float4*)src;
  int idx = blockIdx.x * 256 + threadIdx.x;
  float m = 0.f;
  for (int i = 0; i < 16; ++i) {
    float4 v = s4[idx + i * 65536];
    m = fmaxf(m, fmaxf(fmaxf(fabsf(v.x), fabsf(v.y)), fmaxf(fabsf(v.z), fabsf(v.w))));
  }
  for (int o = 32; o; o >>= 1) m = fmaxf(m, __shfl_down(m, o));
  __shared__ float red[4];
  if ((threadIdx.x & 63) == 0) red[threadIdx.x >> 6] = m;
  __syncthreads();
  if (threadIdx.x == 0) {
    m = fmaxf(fmaxf(red[0], red[1]), fmaxf(red[2], red[3]));
    atomicMax(&scal[blockIdx.y], __float_as_int(m));
  }
}

// quantize to int8 codes (exact)
__global__ void k_quant(const float* __restrict__ x, const float* __restrict__ w1,
                        const float* __restrict__ w2, const float* __restrict__ w3,
                        char* qx, char* qw, const int* scal) {
  int a = blockIdx.y;
  const float* src = (a == 0) ? x : (a == 1) ? w1 : (a == 2) ? w2 : w3;
  char* dst = (a == 0) ? qx : qw + (size_t)(a - 1) * TOKS * EMB;
  float mx = __int_as_float(scal[a]);
  float s = (a == 0) ? mx * 0.25f : mx / 3.0f;
  float lo = (a == 0) ? -4.f : -3.f;
  const float hi = 3.f;
  int idx = blockIdx.x * 256 + threadIdx.x;
  for (int i = 0; i < 16; ++i) {
    int j = idx + i * 65536;
    float4 v = ((const float4*)src)[j];
    int i0 = (int)fminf(fmaxf(rintf(v.x / s), lo), hi);
    int i1 = (int)fminf(fmaxf(rintf(v.y / s), lo), hi);
    int i2 = (int)fminf(fmaxf(rintf(v.z / s), lo), hi);
    int i3 = (int)fminf(fmaxf(rintf(v.w / s), lo), hi);
    unsigned o = (unsigned)(unsigned char)i0 | ((unsigned)(unsigned char)i1 << 8) |
                 ((unsigned)(unsigned char)i2 << 16) | ((unsigned)(unsigned char)i3 << 24);
    ((unsigned*)dst)[j] = o;
  }
}

// Fused QKV GEMM in int8: BM=BN=128, BK=128 i8, 16 K-steps, i32 accum (exact).
__global__ __launch_bounds__(256, 3) void k_gemm(const char* __restrict__ qx, const char* __restrict__ qw,
    const float* __restrict__ b1, const float* __restrict__ b2, const float* __restrict__ b3,
    const int* __restrict__ scal, u16* qo, u16* ko, u16* vo) {
  int z = blockIdx.z;
  const char* W = qw + (size_t)z * TOKS * EMB;
  const float* bias = (z == 0) ? b1 : (z == 1) ? b2 : b3;
  u16* out = (z == 0) ? qo : (z == 1) ? ko : vo;
  float sx = __int_as_float(scal[0]) * 0.25f;
  float sw = __int_as_float(scal[1 + z]) / 3.0f;
  float alpha = sx * sw;
  float extra = (z == 0) ? RSQ : 1.0f;
  int t0 = blockIdx.y * 128, o0 = blockIdx.x * 128;
  __shared__ __align__(16) char As[128 * 128];  // 16KB, rows of 128B (128 i8)
  __shared__ __align__(16) char Bs[128 * 128];
  int tid = threadIdx.x, lane = tid & 63, wid = tid >> 6;
  int mh = (wid >> 1) * 64, nh = (wid & 1) * 64;
  i32x4 acc[4][4] = {};
  for (int kk = 0; kk < 16; ++kk) {
#pragma unroll
    for (int p = 0; p < 4; ++p) {
      int L = p * 4096 + tid * 16;
      int r = L >> 7;
      int s = ((L >> 4) & 7) ^ (r & 7);
      gload16(qx + (size_t)(t0 + r) * 2048 + kk * 128 + s * 16,
              As + p * 4096 + wid * 1024);
      gload16(W + (size_t)(o0 + r) * 2048 + kk * 128 + s * 16,
              Bs + p * 4096 + wid * 1024);
    }
    __syncthreads();
#pragma unroll
    for (int ks = 0; ks < 2; ++ks) {
      i32x4 af[4], bfr[4];
#pragma unroll
      for (int m = 0; m < 4; ++m) {
        int row = mh + m * 16 + (lane & 15);
        int sl = (ks * 4 + (lane >> 4)) ^ (row & 7);
        af[m] = *(const i32x4*)(As + row * 128 + sl * 16);
      }
#pragma unroll
      for (int n = 0; n < 4; ++n) {
        int row = nh + n * 16 + (lane & 15);
        int sl = (ks * 4 + (lane >> 4)) ^ (row & 7);
        bfr[n] = *(const i32x4*)(Bs + row * 128 + sl * 16);
      }
#pragma unroll
      for (int m = 0; m < 4; ++m)
#pragma unroll
        for (int n = 0; n < 4; ++n)
          acc[m][n] = __builtin_amdgcn_mfma_i32_16x16x64_i8(af[m], bfr[n], acc[m][n], 0, 0, 0);
    }
    __syncthreads();
  }
#pragma unroll
  for (int m = 0; m < 4; ++m)
#pragma unroll
    for (int n = 0; n < 4; ++n) {
      int ocol = o0 + nh + n * 16 + (lane & 15);
      float bb = bias[ocol];
#pragma unroll
      for (int r = 0; r < 4; ++r) {
        int trow = t0 + mh + m * 16 + (lane >> 4) * 4 + r;
        float v = ((float)acc[m][n][r] * alpha + bb) * extra;
        out[(size_t)trow * EMB + ocol] = f2b(v);
      }
    }
}

__global__ void k_transpose(const u16* __restrict__ v, u16* vt) {
  int h = blockIdx.z, d0 = blockIdx.y * 64, t0 = blockIdx.x * 64;
  __shared__ u16 tile[64][65];
  int tid = threadIdx.x;
  for (int i = 0; i < 16; ++i) {
    int idx = i * 256 + tid, r = idx >> 6, c = idx & 63;
    tile[r][c] = v[(size_t)(t0 + r) * EMB + h * HS + d0 + c];
  }
  __syncthreads();
  for (int i = 0; i < 16; ++i) {
    int idx = i * 256 + tid, r = idx >> 6, c = idx & 63;
    vt[(size_t)(h * HS + d0 + r) * TOKS + t0 + c] = tile[c][r];
  }
}

// denom: invden[q,k] = 1 / sum_h exp(att[h,q,k]), bf16.
// 64q x 64k per block, grid 1024 (4 blocks/CU @ 32KB), 4 waves 2x2, dbuf LDS.
__global__ __launch_bounds__(256, 4) void k_denom(const u16* __restrict__ q, const u16* __restrict__ k,
                                                  u16* __restrict__ invden) {
  int bid = blockIdx.x;
  int kx = bid & 31, qy = bid >> 5;   // same-XCD blocks share a K stripe
  int qt0 = qy * 64, kt0 = kx * 64;
  __shared__ __align__(16) u16 Qs[2][64 * 64];   // 2 x 8KB
  __shared__ __align__(16) u16 Ksm[2][64 * 64];  // 2 x 8KB
  int tid = threadIdx.x, lane = tid & 63, wid = tid >> 6;
  int wq = (wid >> 1) * 32, wk = (wid & 1) * 32;
  f32x4 acc[2][2] = {}, dd[2][2] = {};
  auto stage = [&](int st, int buf) {
#pragma unroll
    for (int p = 0; p < 2; ++p) {
      int L = p * 4096 + tid * 16;
      int r = L >> 7;
      int s = ((L >> 4) & 7) ^ (r & 7);
      gload16((const char*)q + (size_t)(qt0 + r) * 4096 + st * 128 + s * 16,
              (char*)Qs[buf] + p * 4096 + wid * 1024);
      gload16((const char*)k + (size_t)(kt0 + r) * 4096 + st * 128 + s * 16,
              (char*)Ksm[buf] + p * 4096 + wid * 1024);
    }
  };
  stage(0, 0);
  for (int st = 0; st < 32; ++st) {
    int cur = st & 1;
    if (st < 31) { stage(st + 1, cur ^ 1); VMCNT(4); } else { VMCNT(0); }
    BAR();
    __builtin_amdgcn_s_setprio(1);
#pragma unroll
    for (int ks = 0; ks < 2; ++ks) {
      bf16x8 af[2], bfr[2];
#pragma unroll
      for (int m = 0; m < 2; ++m) {
        int row = wq + m * 16 + (lane & 15);
        int sl = (ks * 4 + (lane >> 4)) ^ (row & 7);
        af[m] = *(const bf16x8*)((const char*)Qs[cur] + row * 128 + sl * 16);
      }
#pragma unroll
      for (int n = 0; n < 2; ++n) {
        int row = wk + n * 16 + (lane & 15);
        int sl = (ks * 4 + (lane >> 4)) ^ (row & 7);
        bfr[n] = *(const bf16x8*)((const char*)Ksm[cur] + row * 128 + sl * 16);
      }
#pragma unroll
      for (int m = 0; m < 2; ++m)
#pragma unroll
        for (int n = 0; n < 2; ++n)
          acc[m][n] = __builtin_amdgcn_mfma_f32_16x16x32_bf16(af[m], bfr[n], acc[m][n], 0, 0, 0);
    }
    __builtin_amdgcn_s_setprio(0);
    BAR();
    if (st & 1) {  // head boundary: fold exp(acc) into dd, reset acc
#pragma unroll
      for (int m = 0; m < 2; ++m)
#pragma unroll
        for (int n = 0; n < 2; ++n) {
#pragma unroll
          for (int r = 0; r < 4; ++r) dd[m][n][r] += __expf(acc[m][n][r]);
          acc[m][n] = f32x4{0.f, 0.f, 0.f, 0.f};
        }
    }
  }
#pragma unroll
  for (int m = 0; m < 2; ++m)
#pragma unroll
    for (int n = 0; n < 2; ++n)
#pragma unroll
      for (int r = 0; r < 4; ++r) {
        int qrow = qt0 + wq + m * 16 + (lane >> 4) * 4 + r;
        int kcol = kt0 + wk + n * 16 + (lane & 15);
        invden[(size_t)qrow * TOKS + kcol] = f2b(1.0f / dd[m][n][r]);
      }
}

// attention: round-9 version (session best). 64q x 1 head per block, grid 512.
// K staged via LDS (dbuf); V^T + invden prefetched to registers (asm, counted
// vmcnt); P double-buffered in LDS. Occupancy capped at 2 blocks/CU by the
// unified VGPR+AGPR budget (~180+ regs) — measured, not fixable without
// losing staging intensity (r11/r12/r14/r15 all regressed).
__global__ __launch_bounds__(256, 2) void k_attn(const u16* __restrict__ q, const u16* __restrict__ k,
                                                 const u16* __restrict__ vt, const u16* __restrict__ invden,
                                                 float* __restrict__ out) {
  int bid = blockIdx.x;
  int h = (bid & 7) * 2 + ((bid >> 3) & 1);  // XCD bid%8 owns a head PAIR -> K/V L2-resident
  int qt0 = (bid >> 4) * 64;
  __shared__ __align__(16) u16 Ks[2][64 * 128];   // 2 x 16KB, rows = k-token (256B)
  __shared__ __align__(16) u16 Ps[2][64 * 64];    // 2 x 8KB, rows = q (128B of 64 k)
  int tid = threadIdx.x, lane = tid & 63, wid = tid >> 6;

  auto stageK = [&](int kb, int buf) {
#pragma unroll
    for (int p = 0; p < 4; ++p) {
      int L = p * 4096 + tid * 16;
      int r = L >> 8;
      int s = ((L >> 4) & 15) ^ (r & 7);
      gload16((const char*)k + (size_t)(kb * 64 + r) * 4096 + h * 256 + s * 16,
              (char*)Ks[buf] + p * 4096 + wid * 1024);
    }
  };
  // per-lane bases for register V^T and invden loads
  const u16* vbase = vt + ((size_t)(h * HS + wid * 32 + (lane & 15))) * TOKS + (lane >> 4) * 8;
  const u16* dvbase = invden + ((size_t)(qt0 + (lane & 15))) * TOKS + wid * 16 + (lane >> 4) * 4;

  bf16x8 vA[4], vB[4];
  u32x2 dvA[4], dvB[4];

  stageK(0, 0);
#pragma unroll
  for (int j = 0; j < 2; ++j)
#pragma unroll
    for (int ks = 0; ks < 2; ++ks)
      vA[j * 2 + ks] = gload_dx4(vbase + (size_t)j * 16 * TOKS + ks * 32);
#pragma unroll
  for (int m = 0; m < 4; ++m)
    dvA[m] = gload_dx2(dvbase + (size_t)m * 16 * TOKS);

  bf16x8 qf[4][4];
#pragma unroll
  for (int m = 0; m < 4; ++m)
#pragma unroll
    for (int c = 0; c < 4; ++c)
      qf[m][c] = *(const bf16x8*)(q + (size_t)(qt0 + m * 16 + (lane & 15)) * EMB
                                  + h * HS + c * 32 + (lane >> 4) * 8);
  f32x4 yacc[4][2] = {};

#define ITER(KB, CUR, VU, VP, DVU, DVP, LAST)                                   \
  {                                                                             \
    if (!(LAST)) {                                                              \
      stageK((KB) + 1, (CUR) ^ 1);                                              \
      _Pragma("unroll")                                                         \
      for (int j = 0; j < 2; ++j)                                               \
        _Pragma("unroll")                                                       \
        for (int ks = 0; ks < 2; ++ks)                                          \
          VP[j * 2 + ks] = gload_dx4(vbase + (size_t)j * 16 * TOKS +            \
                                     ((KB) + 1) * 64 + ks * 32);                \
      _Pragma("unroll")                                                         \
      for (int m = 0; m < 4; ++m)                                               \
        DVP[m] = gload_dx2(dvbase + (size_t)m * 16 * TOKS + ((KB) + 1) * 64);   \
      VMCNT(12);                                                                \
    } else {                                                                    \
      VMCNT(0);                                                                 \
    }                                                                           \
    __builtin_amdgcn_sched_barrier(0);                                          \
    BAR();                                                                      \
    f32x4 pacc[4] = {};                                                         \
    __builtin_amdgcn_s_setprio(1);                                              \
    _Pragma("unroll")                                                           \
    for (int c = 0; c < 4; ++c) {                                               \
      int row = wid * 16 + (lane & 15);                                         \
      int sl = (c * 4 + (lane >> 4)) ^ (row & 7);                               \
      bf16x8 bk = *(const bf16x8*)((const char*)Ks[CUR] + row * 256 + sl * 16); \
      _Pragma("unroll")                                                         \
      for (int m = 0; m < 4; ++m)                                               \
        pacc[m] = __builtin_amdgcn_mfma_f32_16x16x32_bf16(bk, qf[m][c], pacc[m], 0, 0, 0); \
    }                                                                           \
    __builtin_amdgcn_s_setprio(0);                                              \
    _Pragma("unroll")                                                           \
    for (int m = 0; m < 4; ++m) {                                               \
      int qr = m * 16 + (lane & 15);                                            \
      float d0 = __uint_as_float(DVU[m][0] << 16);                              \
      float d1 = __uint_as_float(DVU[m][0] & 0xffff0000u);                      \
      float d2 = __uint_as_float(DVU[m][1] << 16);                              \
      float d3 = __uint_as_float(DVU[m][1] & 0xffff0000u);                      \
      float e0 = __expf(pacc[m][0]) * d0;                                       \
      float e1 = __expf(pacc[m][1]) * d1;                                       \
      float e2 = __expf(pacc[m][2]) * d2;                                       \
      float e3 = __expf(pacc[m][3]) * d3;                                       \
      uint2 pk;                                                                 \
      pk.x = cvtpk(e0, e1);                                                     \
      pk.y = cvtpk(e2, e3);                                                     \
      int kby = wid * 32 + (lane >> 4) * 8;                                     \
      *(uint2*)((char*)Ps[CUR] + qr * 128 + (kby ^ ((qr & 7) << 4))) = pk;      \
    }                                                                           \
    LGKM0();                                                                    \
    BAR();                                                                      \
    __builtin_amdgcn_sched_barrier(0);                                          \
    __builtin_amdgcn_s_setprio(1);                                              \
    _Pragma("unroll")                                                           \
    for (int ks = 0; ks < 2; ++ks) {                                            \
      bf16x8 pa[4];                                                             \
      _Pragma("unroll")                                                         \
      for (int m = 0; m < 4; ++m) {                                             \
        int row = m * 16 + (lane & 15);                                         \
        int off = (ks * 64 + (lane >> 4) * 16) ^ ((row & 7) << 4);              \
        pa[m] = *(const bf16x8*)((const char*)Ps[CUR] + row * 128 + off);       \
      }                                                                         \
      _Pragma("unroll")                                                         \
      for (int m = 0; m < 4; ++m)                                               \
        _Pragma("unroll")                                                       \
        for (int j = 0; j < 2; ++j)                                             \
          yacc[m][j] = __builtin_amdgcn_mfma_f32_16x16x32_bf16(pa[m], VU[j * 2 + ks], yacc[m][j], 0, 0, 0); \
    }                                                                           \
    __builtin_amdgcn_s_setprio(0);                                              \
  }

  for (int t = 0; t < 15; ++t) {
    ITER(2 * t, 0, vA, vB, dvA, dvB, false);
    ITER(2 * t + 1, 1, vB, vA, dvB, dvA, false);
  }
  ITER(30, 0, vA, vB, dvA, dvB, false);
  ITER(31, 1, vB, vA, dvB, dvA, true);
#undef ITER

#pragma unroll
  for (int m = 0; m < 4; ++m)
#pragma unroll
    for (int j = 0; j < 2; ++j)
#pragma unroll
      for (int r = 0; r < 4; ++r) {
        int trow = qt0 + m * 16 + (lane >> 4) * 4 + r;
        int dcol = wid * 32 + j * 16 + (lane & 15);
        out[(size_t)(h * TOKS + trow) * HS + dcol] = yacc[m][j][r];
      }
}

extern "C" void kernel_launch(void* const* d_in, const int* in_sizes, int n_in,
                              void* d_out, int out_size, void* d_ws, size_t ws_size,
                              hipStream_t stream) {
  const float* x  = (const float*)d_in[0];
  const float* W1 = (const float*)d_in[1];
  const float* b1 = (const float*)d_in[2];
  const float* W2 = (const float*)d_in[3];
  const float* b2 = (const float*)d_in[4];
  const float* W3 = (const float*)d_in[5];
  const float* b3 = (const float*)d_in[6];
  char* ws = (char*)d_ws;
  int*   scal   = (int*)(ws + OFF_SCAL);
  char*  qx8    = (char*)(ws + OFF_QX);
  char*  qw8    = (char*)(ws + OFF_QW);
  u16*   qo     = (u16*)(ws + OFF_Q);
  u16*   ko     = (u16*)(ws + OFF_K);
  u16*   vo     = (u16*)(ws + OFF_V);
  u16*   vt     = (u16*)(ws + OFF_VT);
  u16*   invden = (u16*)(ws + OFF_DEN);
  float* y      = (float*)d_out;

  hipLaunchKernelGGL(k_init, dim3(1), dim3(64), 0, stream, scal);
  hipLaunchKernelGGL(k_absmax, dim3(256, 4), dim3(256), 0, stream, x, W1, W2, W3, scal);
  hipLaunchKernelGGL(k_quant, dim3(256, 4), dim3(256), 0, stream, x, W1, W2, W3, qx8, qw8, scal);
  hipLaunchKernelGGL(k_gemm, dim3(16, 16, 3), dim3(256), 0, stream,
                     qx8, qw8, b1, b2, b3, scal, qo, ko, vo);
  hipLaunchKernelGGL(k_transpose, dim3(32, 2, 16), dim3(256), 0, stream, vo, vt);
  hipLaunchKernelGGL(k_denom, dim3(1024), dim3(256), 0, stream, qo, ko, invden);
  hipLaunchKernelGGL(k_attn, dim3(512), dim3(256), 0, stream, qo, ko, vt, invden, y);
}

// Round 17
// 171.680 us; speedup vs baseline: 1.2261x; 1.0219x over previous
//
#include <hip/hip_runtime.h>
#include <hip/hip_bf16.h>

typedef short bf16x8 __attribute__((ext_vector_type(8)));
typedef float f32x4 __attribute__((ext_vector_type(4)));
typedef int   i32x4 __attribute__((ext_vector_type(4)));
typedef unsigned u32x2 __attribute__((ext_vector_type(2)));
typedef unsigned short u16;

constexpr int TOKS = 2048;
constexpr int EMB  = 2048;
constexpr int NH   = 16;
constexpr int HS   = 128;
constexpr float RSQ = 0.08838834764831845f; // 1/sqrt(128)

// workspace layout (bytes)
constexpr size_t OFF_SCAL = 0;                       // 4 floats (absmax)
constexpr size_t OFF_QX   = 1024;                    // int8 x [T,EMB] (4MB used)
constexpr size_t SZ_MAT   = (size_t)TOKS * EMB * 2;  // 8MB bf16
constexpr size_t OFF_QW   = OFF_QX + SZ_MAT;         // int8 x 3 mats (12MB used)
constexpr size_t OFF_Q    = OFF_QW + 3 * SZ_MAT;
constexpr size_t OFF_K    = OFF_Q + SZ_MAT;
constexpr size_t OFF_V    = OFF_K + SZ_MAT;
constexpr size_t OFF_VT   = OFF_V + SZ_MAT;
constexpr size_t OFF_DEN  = OFF_VT + SZ_MAT;         // invden, 8MB bf16

#define VMCNT(n) asm volatile("s_waitcnt vmcnt(" #n ")" ::: "memory")
#define LGKM0()  asm volatile("s_waitcnt lgkmcnt(0)" ::: "memory")
#define BAR()    do { asm volatile("" ::: "memory"); __builtin_amdgcn_s_barrier(); asm volatile("" ::: "memory"); } while (0)

__device__ __forceinline__ u16 f2b(float f) {
  unsigned u = __float_as_uint(f);
  unsigned r = (u + 0x7fffu + ((u >> 16) & 1u)) >> 16;
  return (u16)r;
}

__device__ __forceinline__ unsigned cvtpk(float a, float b) {
  unsigned r;
  asm("v_cvt_pk_bf16_f32 %0, %1, %2" : "=v"(r) : "v"(a), "v"(b));
  return r;
}

__device__ __forceinline__ void gload16(const void* g, void* l) {
  __builtin_amdgcn_global_load_lds(
      (const __attribute__((address_space(1))) unsigned int*)g,
      (__attribute__((address_space(3))) unsigned int*)l, 16, 0, 0);
}

// untracked register loads (counted only by our manual VMCNT)
__device__ __forceinline__ bf16x8 gload_dx4(const void* p) {
  bf16x8 r;
  asm volatile("global_load_dwordx4 %0, %1, off" : "=v"(r) : "v"(p));
  return r;
}
__device__ __forceinline__ u32x2 gload_dx2(const void* p) {
  u32x2 r;
  asm volatile("global_load_dwordx2 %0, %1, off" : "=v"(r) : "v"(p));
  return r;
}

__global__ void k_init(int* scal) {
  if (threadIdx.x < 4) scal[threadIdx.x] = 0;
}

__global__ void k_absmax(const float* __restrict__ x, const float* __restrict__ w1,
                         const float* __restrict__ w2, const float* __restrict__ w3,
                         int* scal) {
  const float* src = (blockIdx.y == 0) ? x : (blockIdx.y == 1) ? w1 : (blockIdx.y == 2) ? w2 : w3;
  const float4* s4 = (const float4*)src;
  int idx = blockIdx.x * 256 + threadIdx.x;
  float m = 0.f;
  for (int i = 0; i < 16; ++i) {
    float4 v = s4[idx + i * 65536];
    m = fmaxf(m, fmaxf(fmaxf(fabsf(v.x), fabsf(v.y)), fmaxf(fabsf(v.z), fabsf(v.w))));
  }
  for (int o = 32; o; o >>= 1) m = fmaxf(m, __shfl_down(m, o));
  __shared__ float red[4];
  if ((threadIdx.x & 63) == 0) red[threadIdx.x >> 6] = m;
  __syncthreads();
  if (threadIdx.x == 0) {
    m = fmaxf(fmaxf(red[0], red[1]), fmaxf(red[2], red[3]));
    atomicMax(&scal[blockIdx.y], __float_as_int(m));
  }
}

// quantize to int8 codes (exact)
__global__ void k_quant(const float* __restrict__ x, const float* __restrict__ w1,
                        const float* __restrict__ w2, const float* __restrict__ w3,
                        char* qx, char* qw, const int* scal) {
  int a = blockIdx.y;
  const float* src = (a == 0) ? x : (a == 1) ? w1 : (a == 2) ? w2 : w3;
  char* dst = (a == 0) ? qx : qw + (size_t)(a - 1) * TOKS * EMB;
  float mx = __int_as_float(scal[a]);
  float s = (a == 0) ? mx * 0.25f : mx / 3.0f;
  float lo = (a == 0) ? -4.f : -3.f;
  const float hi = 3.f;
  int idx = blockIdx.x * 256 + threadIdx.x;
  for (int i = 0; i < 16; ++i) {
    int j = idx + i * 65536;
    float4 v = ((const float4*)src)[j];
    int i0 = (int)fminf(fmaxf(rintf(v.x / s), lo), hi);
    int i1 = (int)fminf(fmaxf(rintf(v.y / s), lo), hi);
    int i2 = (int)fminf(fmaxf(rintf(v.z / s), lo), hi);
    int i3 = (int)fminf(fmaxf(rintf(v.w / s), lo), hi);
    unsigned o = (unsigned)(unsigned char)i0 | ((unsigned)(unsigned char)i1 << 8) |
                 ((unsigned)(unsigned char)i2 << 16) | ((unsigned)(unsigned char)i3 << 24);
    ((unsigned*)dst)[j] = o;
  }
}

// Fused QKV GEMM in int8: BM=BN=128, BK=128 i8, 16 K-steps, i32 accum (exact).
// z==2 (V) writes DIRECTLY in vt layout [h][d][t] (packed ushort4 over the 4
// consecutive trow) — absorbs the old k_transpose kernel (saves 32MB traffic
// + a launch; same 32B-segment store pattern as the token-major epilogue).
__global__ __launch_bounds__(256, 3) void k_gemm(const char* __restrict__ qx, const char* __restrict__ qw,
    const float* __restrict__ b1, const float* __restrict__ b2, const float* __restrict__ b3,
    const int* __restrict__ scal, u16* qo, u16* ko, u16* vt) {
  int z = blockIdx.z;
  const char* W = qw + (size_t)z * TOKS * EMB;
  const float* bias = (z == 0) ? b1 : (z == 1) ? b2 : b3;
  u16* out = (z == 0) ? qo : ko;  // z==2 uses vt path below
  float sx = __int_as_float(scal[0]) * 0.25f;
  float sw = __int_as_float(scal[1 + z]) / 3.0f;
  float alpha = sx * sw;
  float extra = (z == 0) ? RSQ : 1.0f;
  int t0 = blockIdx.y * 128, o0 = blockIdx.x * 128;
  __shared__ __align__(16) char As[128 * 128];  // 16KB, rows of 128B (128 i8)
  __shared__ __align__(16) char Bs[128 * 128];
  int tid = threadIdx.x, lane = tid & 63, wid = tid >> 6;
  int mh = (wid >> 1) * 64, nh = (wid & 1) * 64;
  i32x4 acc[4][4] = {};
  for (int kk = 0; kk < 16; ++kk) {
#pragma unroll
    for (int p = 0; p < 4; ++p) {
      int L = p * 4096 + tid * 16;
      int r = L >> 7;
      int s = ((L >> 4) & 7) ^ (r & 7);
      gload16(qx + (size_t)(t0 + r) * 2048 + kk * 128 + s * 16,
              As + p * 4096 + wid * 1024);
      gload16(W + (size_t)(o0 + r) * 2048 + kk * 128 + s * 16,
              Bs + p * 4096 + wid * 1024);
    }
    __syncthreads();
#pragma unroll
    for (int ks = 0; ks < 2; ++ks) {
      i32x4 af[4], bfr[4];
#pragma unroll
      for (int m = 0; m < 4; ++m) {
        int row = mh + m * 16 + (lane & 15);
        int sl = (ks * 4 + (lane >> 4)) ^ (row & 7);
        af[m] = *(const i32x4*)(As + row * 128 + sl * 16);
      }
#pragma unroll
      for (int n = 0; n < 4; ++n) {
        int row = nh + n * 16 + (lane & 15);
        int sl = (ks * 4 + (lane >> 4)) ^ (row & 7);
        bfr[n] = *(const i32x4*)(Bs + row * 128 + sl * 16);
      }
#pragma unroll
      for (int m = 0; m < 4; ++m)
#pragma unroll
        for (int n = 0; n < 4; ++n)
          acc[m][n] = __builtin_amdgcn_mfma_i32_16x16x64_i8(af[m], bfr[n], acc[m][n], 0, 0, 0);
    }
    __syncthreads();
  }
  if (z == 2) {
    // V epilogue: write vt[h*128+d][t], 4 consecutive t packed per store
#pragma unroll
    for (int m = 0; m < 4; ++m)
#pragma unroll
      for (int n = 0; n < 4; ++n) {
        int ocol = o0 + nh + n * 16 + (lane & 15);
        float bb = bias[ocol];
        int trow = t0 + mh + m * 16 + (lane >> 4) * 4;
        ushort4 pk;
        pk.x = f2b((float)acc[m][n][0] * alpha + bb);
        pk.y = f2b((float)acc[m][n][1] * alpha + bb);
        pk.z = f2b((float)acc[m][n][2] * alpha + bb);
        pk.w = f2b((float)acc[m][n][3] * alpha + bb);
        *(ushort4*)&vt[(size_t)ocol * TOKS + trow] = pk;
      }
  } else {
#pragma unroll
    for (int m = 0; m < 4; ++m)
#pragma unroll
      for (int n = 0; n < 4; ++n) {
        int ocol = o0 + nh + n * 16 + (lane & 15);
        float bb = bias[ocol];
#pragma unroll
        for (int r = 0; r < 4; ++r) {
          int trow = t0 + mh + m * 16 + (lane >> 4) * 4 + r;
          float v = ((float)acc[m][n][r] * alpha + bb) * extra;
          out[(size_t)trow * EMB + ocol] = f2b(v);
        }
      }
  }
}

// denom: invden[q,k] = 1 / sum_h exp(att[h,q,k]), bf16.
// 64q x 64k per block, grid 1024 (4 blocks/CU @ 32KB), 4 waves 2x2, dbuf LDS.
__global__ __launch_bounds__(256, 4) void k_denom(const u16* __restrict__ q, const u16* __restrict__ k,
                                                  u16* __restrict__ invden) {
  int bid = blockIdx.x;
  int kx = bid & 31, qy = bid >> 5;   // same-XCD blocks share a K stripe
  int qt0 = qy * 64, kt0 = kx * 64;
  __shared__ __align__(16) u16 Qs[2][64 * 64];   // 2 x 8KB
  __shared__ __align__(16) u16 Ksm[2][64 * 64];  // 2 x 8KB
  int tid = threadIdx.x, lane = tid & 63, wid = tid >> 6;
  int wq = (wid >> 1) * 32, wk = (wid & 1) * 32;
  f32x4 acc[2][2] = {}, dd[2][2] = {};
  auto stage = [&](int st, int buf) {
#pragma unroll
    for (int p = 0; p < 2; ++p) {
      int L = p * 4096 + tid * 16;
      int r = L >> 7;
      int s = ((L >> 4) & 7) ^ (r & 7);
      gload16((const char*)q + (size_t)(qt0 + r) * 4096 + st * 128 + s * 16,
              (char*)Qs[buf] + p * 4096 + wid * 1024);
      gload16((const char*)k + (size_t)(kt0 + r) * 4096 + st * 128 + s * 16,
              (char*)Ksm[buf] + p * 4096 + wid * 1024);
    }
  };
  stage(0, 0);
  for (int st = 0; st < 32; ++st) {
    int cur = st & 1;
    if (st < 31) { stage(st + 1, cur ^ 1); VMCNT(4); } else { VMCNT(0); }
    BAR();
    __builtin_amdgcn_s_setprio(1);
#pragma unroll
    for (int ks = 0; ks < 2; ++ks) {
      bf16x8 af[2], bfr[2];
#pragma unroll
      for (int m = 0; m < 2; ++m) {
        int row = wq + m * 16 + (lane & 15);
        int sl = (ks * 4 + (lane >> 4)) ^ (row & 7);
        af[m] = *(const bf16x8*)((const char*)Qs[cur] + row * 128 + sl * 16);
      }
#pragma unroll
      for (int n = 0; n < 2; ++n) {
        int row = wk + n * 16 + (lane & 15);
        int sl = (ks * 4 + (lane >> 4)) ^ (row & 7);
        bfr[n] = *(const bf16x8*)((const char*)Ksm[cur] + row * 128 + sl * 16);
      }
#pragma unroll
      for (int m = 0; m < 2; ++m)
#pragma unroll
        for (int n = 0; n < 2; ++n)
          acc[m][n] = __builtin_amdgcn_mfma_f32_16x16x32_bf16(af[m], bfr[n], acc[m][n], 0, 0, 0);
    }
    __builtin_amdgcn_s_setprio(0);
    BAR();
    if (st & 1) {  // head boundary: fold exp(acc) into dd, reset acc
#pragma unroll
      for (int m = 0; m < 2; ++m)
#pragma unroll
        for (int n = 0; n < 2; ++n) {
#pragma unroll
          for (int r = 0; r < 4; ++r) dd[m][n][r] += __expf(acc[m][n][r]);
          acc[m][n] = f32x4{0.f, 0.f, 0.f, 0.f};
        }
    }
  }
#pragma unroll
  for (int m = 0; m < 2; ++m)
#pragma unroll
    for (int n = 0; n < 2; ++n)
#pragma unroll
      for (int r = 0; r < 4; ++r) {
        int qrow = qt0 + wq + m * 16 + (lane >> 4) * 4 + r;
        int kcol = kt0 + wk + n * 16 + (lane & 15);
        invden[(size_t)qrow * TOKS + kcol] = f2b(1.0f / dd[m][n][r]);
      }
}

// attention: session-best version. 64q x 1 head per block, grid 512.
// K staged via LDS (dbuf); V^T + invden prefetched to registers (asm, counted
// vmcnt); P double-buffered in LDS. Occupancy capped at 2 blocks/CU by the
// unified VGPR+AGPR budget (~180+ regs).
__global__ __launch_bounds__(256, 2) void k_attn(const u16* __restrict__ q, const u16* __restrict__ k,
                                                 const u16* __restrict__ vt, const u16* __restrict__ invden,
                                                 float* __restrict__ out) {
  int bid = blockIdx.x;
  int h = (bid & 7) * 2 + ((bid >> 3) & 1);  // XCD bid%8 owns a head PAIR -> K/V L2-resident
  int qt0 = (bid >> 4) * 64;
  __shared__ __align__(16) u16 Ks[2][64 * 128];   // 2 x 16KB, rows = k-token (256B)
  __shared__ __align__(16) u16 Ps[2][64 * 64];    // 2 x 8KB, rows = q (128B of 64 k)
  int tid = threadIdx.x, lane = tid & 63, wid = tid >> 6;

  auto stageK = [&](int kb, int buf) {
#pragma unroll
    for (int p = 0; p < 4; ++p) {
      int L = p * 4096 + tid * 16;
      int r = L >> 8;
      int s = ((L >> 4) & 15) ^ (r & 7);
      gload16((const char*)k + (size_t)(kb * 64 + r) * 4096 + h * 256 + s * 16,
              (char*)Ks[buf] + p * 4096 + wid * 1024);
    }
  };
  // per-lane bases for register V^T and invden loads
  const u16* vbase = vt + ((size_t)(h * HS + wid * 32 + (lane & 15))) * TOKS + (lane >> 4) * 8;
  const u16* dvbase = invden + ((size_t)(qt0 + (lane & 15))) * TOKS + wid * 16 + (lane >> 4) * 4;

  bf16x8 vA[4], vB[4];
  u32x2 dvA[4], dvB[4];

  stageK(0, 0);
#pragma unroll
  for (int j = 0; j < 2; ++j)
#pragma unroll
    for (int ks = 0; ks < 2; ++ks)
      vA[j * 2 + ks] = gload_dx4(vbase + (size_t)j * 16 * TOKS + ks * 32);
#pragma unroll
  for (int m = 0; m < 4; ++m)
    dvA[m] = gload_dx2(dvbase + (size_t)m * 16 * TOKS);

  bf16x8 qf[4][4];
#pragma unroll
  for (int m = 0; m < 4; ++m)
#pragma unroll
    for (int c = 0; c < 4; ++c)
      qf[m][c] = *(const bf16x8*)(q + (size_t)(qt0 + m * 16 + (lane & 15)) * EMB
                                  + h * HS + c * 32 + (lane >> 4) * 8);
  f32x4 yacc[4][2] = {};

#define ITER(KB, CUR, VU, VP, DVU, DVP, LAST)                                   \
  {                                                                             \
    if (!(LAST)) {                                                              \
      stageK((KB) + 1, (CUR) ^ 1);                                              \
      _Pragma("unroll")                                                         \
      for (int j = 0; j < 2; ++j)                                               \
        _Pragma("unroll")                                                       \
        for (int ks = 0; ks < 2; ++ks)                                          \
          VP[j * 2 + ks] = gload_dx4(vbase + (size_t)j * 16 * TOKS +            \
                                     ((KB) + 1) * 64 + ks * 32);                \
      _Pragma("unroll")                                                         \
      for (int m = 0; m < 4; ++m)                                               \
        DVP[m] = gload_dx2(dvbase + (size_t)m * 16 * TOKS + ((KB) + 1) * 64);   \
      VMCNT(12);                                                                \
    } else {                                                                    \
      VMCNT(0);                                                                 \
    }                                                                           \
    __builtin_amdgcn_sched_barrier(0);                                          \
    BAR();                                                                      \
    f32x4 pacc[4] = {};                                                         \
    __builtin_amdgcn_s_setprio(1);                                              \
    _Pragma("unroll")                                                           \
    for (int c = 0; c < 4; ++c) {                                               \
      int row = wid * 16 + (lane & 15);                                         \
      int sl = (c * 4 + (lane >> 4)) ^ (row & 7);                               \
      bf16x8 bk = *(const bf16x8*)((const char*)Ks[CUR] + row * 256 + sl * 16); \
      _Pragma("unroll")                                                         \
      for (int m = 0; m < 4; ++m)                                               \
        pacc[m] = __builtin_amdgcn_mfma_f32_16x16x32_bf16(bk, qf[m][c], pacc[m], 0, 0, 0); \
    }                                                                           \
    __builtin_amdgcn_s_setprio(0);                                              \
    _Pragma("unroll")                                                           \
    for (int m = 0; m < 4; ++m) {                                               \
      int qr = m * 16 + (lane & 15);                                            \
      float d0 = __uint_as_float(DVU[m][0] << 16);                              \
      float d1 = __uint_as_float(DVU[m][0] & 0xffff0000u);                      \
      float d2 = __uint_as_float(DVU[m][1] << 16);                              \
      float d3 = __uint_as_float(DVU[m][1] & 0xffff0000u);                      \
      float e0 = __expf(pacc[m][0]) * d0;                                       \
      float e1 = __expf(pacc[m][1]) * d1;                                       \
      float e2 = __expf(pacc[m][2]) * d2;                                       \
      float e3 = __expf(pacc[m][3]) * d3;                                       \
      uint2 pk;                                                                 \
      pk.x = cvtpk(e0, e1);                                                     \
      pk.y = cvtpk(e2, e3);                                                     \
      int kby = wid * 32 + (lane >> 4) * 8;                                     \
      *(uint2*)((char*)Ps[CUR] + qr * 128 + (kby ^ ((qr & 7) << 4))) = pk;      \
    }                                                                           \
    LGKM0();                                                                    \
    BAR();                                                                      \
    __builtin_amdgcn_sched_barrier(0);                                          \
    __builtin_amdgcn_s_setprio(1);                                              \
    _Pragma("unroll")                                                           \
    for (int ks = 0; ks < 2; ++ks) {                                            \
      bf16x8 pa[4];                                                             \
      _Pragma("unroll")                                                         \
      for (int m = 0; m < 4; ++m) {                                             \
        int row = m * 16 + (lane & 15);                                         \
        int off = (ks * 64 + (lane >> 4) * 16) ^ ((row & 7) << 4);              \
        pa[m] = *(const bf16x8*)((const char*)Ps[CUR] + row * 128 + off);       \
      }                                                                         \
      _Pragma("unroll")                                                         \
      for (int m = 0; m < 4; ++m)                                               \
        _Pragma("unroll")                                                       \
        for (int j = 0; j < 2; ++j)                                             \
          yacc[m][j] = __builtin_amdgcn_mfma_f32_16x16x32_bf16(pa[m], VU[j * 2 + ks], yacc[m][j], 0, 0, 0); \
    }                                                                           \
    __builtin_amdgcn_s_setprio(0);                                              \
  }

  for (int t = 0; t < 15; ++t) {
    ITER(2 * t, 0, vA, vB, dvA, dvB, false);
    ITER(2 * t + 1, 1, vB, vA, dvB, dvA, false);
  }
  ITER(30, 0, vA, vB, dvA, dvB, false);
  ITER(31, 1, vB, vA, dvB, dvA, true);
#undef ITER

#pragma unroll
  for (int m = 0; m < 4; ++m)
#pragma unroll
    for (int j = 0; j < 2; ++j)
#pragma unroll
      for (int r = 0; r < 4; ++r) {
        int trow = qt0 + m * 16 + (lane >> 4) * 4 + r;
        int dcol = wid * 32 + j * 16 + (lane & 15);
        out[(size_t)(h * TOKS + trow) * HS + dcol] = yacc[m][j][r];
      }
}

extern "C" void kernel_launch(void* const* d_in, const int* in_sizes, int n_in,
                              void* d_out, int out_size, void* d_ws, size_t ws_size,
                              hipStream_t stream) {
  const float* x  = (const float*)d_in[0];
  const float* W1 = (const float*)d_in[1];
  const float* b1 = (const float*)d_in[2];
  const float* W2 = (const float*)d_in[3];
  const float* b2 = (const float*)d_in[4];
  const float* W3 = (const float*)d_in[5];
  const float* b3 = (const float*)d_in[6];
  char* ws = (char*)d_ws;
  int*   scal   = (int*)(ws + OFF_SCAL);
  char*  qx8    = (char*)(ws + OFF_QX);
  char*  qw8    = (char*)(ws + OFF_QW);
  u16*   qo     = (u16*)(ws + OFF_Q);
  u16*   ko     = (u16*)(ws + OFF_K);
  u16*   vt     = (u16*)(ws + OFF_VT);
  u16*   invden = (u16*)(ws + OFF_DEN);
  float* y      = (float*)d_out;

  hipLaunchKernelGGL(k_init, dim3(1), dim3(64), 0, stream, scal);
  hipLaunchKernelGGL(k_absmax, dim3(256, 4), dim3(256), 0, stream, x, W1, W2, W3, scal);
  hipLaunchKernelGGL(k_quant, dim3(256, 4), dim3(256), 0, stream, x, W1, W2, W3, qx8, qw8, scal);
  hipLaunchKernelGGL(k_gemm, dim3(16, 16, 3), dim3(256), 0, stream,
                     qx8, qw8, b1, b2, b3, scal, qo, ko, vt);
  hipLaunchKernelGGL(k_denom, dim3(1024), dim3(256), 0, stream, qo, ko, invden);
  hipLaunchKernelGGL(k_attn, dim3(512), dim3(256), 0, stream, qo, ko, vt, invden, y);
}